// Round 15
// baseline (253.742 us; speedup 1.0000x reference)
//
#include <hip/hip_runtime.h>
#include <hip/hip_bf16.h>
#include <math.h>

typedef __hip_bfloat16 bf16;
typedef __attribute__((ext_vector_type(8))) short frag8;
typedef __attribute__((ext_vector_type(4))) float f32x4;

#define HW  1296
#define CH  128
#define TT  1327104   // 8 * 1296 * 128
#define LOG2E 1.4426950408889634f

__device__ __forceinline__ float b2f(bf16 v) { return __bfloat162float(v); }
__device__ __forceinline__ float bits2f(unsigned short u) {
    return __uint_as_float(((unsigned)u) << 16);
}
__device__ __forceinline__ float frcp(float x) { return __builtin_amdgcn_rcpf(x); }
__device__ __forceinline__ float fsigm(float x) { return frcp(1.0f + __expf(-x)); }
__device__ __forceinline__ float ftanh(float x) {
    float xc = fminf(15.0f, fmaxf(-15.0f, x));
    float e = __expf(2.0f * xc);
    return (e - 1.0f) * frcp(e + 1.0f);
}
// round-half-up f32->bf16 pair pack: 2 adds + 1 v_perm
__device__ __forceinline__ int packrh(float a, float b) {
    unsigned ua = __float_as_uint(a) + 0x8000u;
    unsigned ub = __float_as_uint(b) + 0x8000u;
    return (int)__builtin_amdgcn_perm(ub, ua, 0x07060302);
}
__device__ __forceinline__ int2 pack4(float a, float b, float c, float d) {
    int2 r; r.x = packrh(a, b); r.y = packrh(c, d); return r;
}

// inline wave-uniform dtype detection (256 probe elems of w_in)
__device__ __forceinline__ int detect_f32(const void* w) {
    const short4* p = (const short4*)w;
    short4 v = p[threadIdx.x & 63];
    int bad = 0;
    #pragma unroll
    for (int j = 0; j < 4; ++j) {
        float f = bits2f(((const unsigned short*)&v)[j]);
        if (!(fabsf(f) <= 100.0f)) bad = 1;
    }
    return __any(bad) ? 1 : 0;
}

// ---------------- weight prep ----------------
// Wst (bf16): w_in[128o][128i]@0 | wconvT[9tap][128o][128r]@16384 |
//   wqkv[384o][128i]@163840 | wg[3][128o][256k]@212992 | wout[128o][128i]@311296
// Bst f32[768]: in@0 conv@128 i@256 g@384 o@512 out@640
__global__ __launch_bounds__(256) void k_prep(
    const void* w_in, const void* w_conv, const void* wq, const void* wk, const void* wv,
    const void* w_i, const void* w_g, const void* w_o, const void* w_out,
    const void* b_in, const void* b_conv, const void* b_i, const void* b_g,
    const void* b_o, const void* b_out,
    bf16* __restrict__ Wdst, float* __restrict__ Bdst)
{
    int idx = blockIdx.x * 256 + threadIdx.x;
    const int f = detect_f32(w_in);
    if (idx < 327680) {
        const void* src; int si;
        if (idx < 16384)       { src = w_in; si = idx; }
        else if (idx < 163840) { int j = idx - 16384; int tap = j >> 14, rem = j & 16383;
                                 int o = rem >> 7, r = rem & 127;
                                 src = w_conv; si = o * 2304 + r * 9 + tap; }
        else if (idx < 212992) { int j = idx - 163840; int o = j >> 7, i = j & 127;
                                 int ws_ = o >> 7;
                                 src = ws_ == 0 ? wq : ws_ == 1 ? wk : wv;
                                 si = (o & 127) * 128 + i; }
        else if (idx < 311296) { int j = idx - 212992; int g = j >> 15, rem = j & 32767;
                                 int o = rem >> 8, k = rem & 255;
                                 src = g == 0 ? w_i : g == 1 ? w_g : w_o; si = o * 256 + k; }
        else                   { int j = idx - 311296; int o = j >> 7, i = j & 127;
                                 src = w_out; si = o * 128 + i; }
        float v = f ? ((const float*)src)[si] : b2f(((const bf16*)src)[si]);
        Wdst[idx] = __float2bfloat16(v);
    } else if (idx < 327680 + 768) {
        int j = idx - 327680; int b = j >> 7, e = j & 127;
        const void* src = b == 0 ? b_in : b == 1 ? b_conv : b == 2 ? b_i
                        : b == 3 ? b_g : b == 4 ? b_o : b_out;
        Bdst[j] = f ? ((const float*)src)[e] : b2f(((const bf16*)src)[e]);
    }
}

// ---------------- k_inm: fused transpose + MFMA GEMM + tanh (unchanged) ----------------
__global__ __launch_bounds__(256) void k_inm(const void* __restrict__ x,
                                             const void* __restrict__ wraw,
                                             const bf16* __restrict__ Wm,
                                             const float* __restrict__ bias,
                                             bf16* __restrict__ XT) {
    __shared__ short Xl[32][132];
    const int tid = threadIdx.x, wave = tid >> 6, lane = tid & 63;
    const int quad = lane >> 4, l16 = lane & 15;
    const int n = blockIdx.x;
    const int pbase = blockIdx.y * 32;
    const int obase = blockIdx.z * 32 + (wave & 1) * 16;
    const int pstrip = (wave >> 1) * 16;
    const int f = detect_f32(wraw);

    #pragma unroll
    for (int rep = 0; rep < 4; ++rep) {
        int u = tid + rep * 256;
        int i = u >> 3;
        int p4 = (u & 7) * 4;
        int p = pbase + p4;
        short4 s = {0, 0, 0, 0};
        if (p < HW) {
            size_t gi = (size_t)n * CH * HW + (size_t)i * HW + p;
            if (f) {
                float4 fv = *(const float4*)((const float*)x + gi);
                int2 pk = pack4(fv.x, fv.y, fv.z, fv.w);
                s = *(short4*)&pk;
            } else {
                s = *(const short4*)((const bf16*)x + gi);
            }
        }
        Xl[p4 + 0][i] = s.x; Xl[p4 + 1][i] = s.y;
        Xl[p4 + 2][i] = s.z; Xl[p4 + 3][i] = s.w;
    }
    __syncthreads();

    const int pl = pstrip + l16;
    f32x4 acc = {0.f, 0.f, 0.f, 0.f};
    #pragma unroll
    for (int kc = 0; kc < 4; ++kc) {
        int k = kc * 32 + quad * 8;
        short4 b0 = *(const short4*)&Xl[pl][k];
        short4 b1 = *(const short4*)&Xl[pl][k + 4];
        frag8 bf = {b0.x, b0.y, b0.z, b0.w, b1.x, b1.y, b1.z, b1.w};
        frag8 wf = *(const frag8*)&Wm[(obase + l16) * CH + k];
        acc = __builtin_amdgcn_mfma_f32_16x16x32_bf16(wf, bf, acc, 0, 0, 0);
    }

    int p = pbase + pstrip + l16;
    if (p < HW) {
        int og = obase + quad * 4;
        int2 pk = pack4(ftanh(acc[0] + bias[og + 0]), ftanh(acc[1] + bias[og + 1]),
                        ftanh(acc[2] + bias[og + 2]), ftanh(acc[3] + bias[og + 3]));
        *(int2*)((short*)XT + ((size_t)n * HW + p) * CH + og) = pk;
    }
}

// ---------------- k_cq: fused conv3x3 + qkv, 1024 threads, 32p x all-o per block -------
// phase 1: 16 waves cover 128o x 32p conv (wave = 16o x 16p); z -> global + LDS
// phase 2: wave (pq = w&1, s0 = w>>1) computes qkv o-strips {s0, s0+8, s0+16} for its
//   16 p from LDS z. s<8: Q (scaled by LOG2E, head-grouped); s<16: K; else V (channel-
//   first via swapped-operand MFMA).
__global__ __launch_bounds__(1024) void k_cq(const bf16* __restrict__ XT,
                                             const bf16* __restrict__ Wconv,
                                             const bf16* __restrict__ Wqkv,
                                             const float* __restrict__ biasc,
                                             bf16* __restrict__ Zb,
                                             bf16* __restrict__ Qg,
                                             bf16* __restrict__ Kg,
                                             bf16* __restrict__ Vcf) {
    __shared__ short Zl[32][132];
    const int tid = threadIdx.x, w = tid >> 6, lane = tid & 63;
    const int quad = lane >> 4, l16 = lane & 15;
    const int n = blockIdx.x;
    const int pb = blockIdx.y * 32;
    const bf16* actn = XT + (size_t)n * HW * CH;
    frag8 zf = {0, 0, 0, 0, 0, 0, 0, 0};

    // ---- conv phase ----
    {
        const int obase = (w & 7) * 16, pl0 = (w >> 3) * 16;
        const int p1 = pb + pl0 + l16;
        const bool ok = p1 < HW;
        const int h1 = p1 / 36, w1 = p1 - h1 * 36;
        f32x4 acc = {0.f, 0.f, 0.f, 0.f};
        #pragma unroll
        for (int tap = 0; tap < 9; ++tap) {
            int dy = tap / 3 - 1, dx = tap - (tap / 3) * 3 - 1;
            bool ok1 = ok && (unsigned)(h1 + dy) < 36u && (unsigned)(w1 + dx) < 36u;
            int sh = dy * 36 + dx;
            const bf16* a1 = actn + (size_t)(p1 + sh) * CH + quad * 8;
            const bf16* wp = Wconv + tap * 16384 + (obase + l16) * CH + quad * 8;
            #pragma unroll
            for (int kc = 0; kc < 4; ++kc) {
                frag8 bf1 = zf;
                if (ok1) bf1 = *(const frag8*)&a1[kc * 32];
                frag8 wf = *(const frag8*)&wp[kc * 32];
                acc = __builtin_amdgcn_mfma_f32_16x16x32_bf16(wf, bf1, acc, 0, 0, 0);
            }
        }
        int og = obase + quad * 4;
        int2 zpk = {0, 0};
        if (ok) {
            zpk = pack4(acc[0] + biasc[og + 0], acc[1] + biasc[og + 1],
                        acc[2] + biasc[og + 2], acc[3] + biasc[og + 3]);
            *(int2*)((short*)Zb + ((size_t)n * HW + p1) * CH + og) = zpk;
        }
        *(int2*)&Zl[pl0 + l16][og] = zpk;
    }
    __syncthreads();

    // ---- qkv phase ----
    {
        const int pq = w & 1, s0 = w >> 1;     // s0: 0..7
        const int pl = pq * 16 + l16;
        const int p = pb + pl;
        const bool pok = p < HW;
        frag8 bq[4];
        #pragma unroll
        for (int kc = 0; kc < 4; ++kc)
            bq[kc] = *(const frag8*)&Zl[pl][kc * 32 + quad * 8];
        #pragma unroll
        for (int j = 0; j < 3; ++j) {
            const int s = s0 + j * 8;          // 0..7 Q, 8..15 K, 16..23 V
            const bf16* wp = Wqkv + (s * 16 + l16) * CH + quad * 8;
            f32x4 a = {0.f, 0.f, 0.f, 0.f};
            if (s < 16) {
                #pragma unroll
                for (int kc = 0; kc < 4; ++kc) {
                    frag8 wf = *(const frag8*)&wp[kc * 32];
                    a = __builtin_amdgcn_mfma_f32_16x16x32_bf16(wf, bq[kc], a, 0, 0, 0);
                }
                if (pok) {
                    if (s < 8) {   // Q, pre-scaled by LOG2E for exp2 softmax
                        int2 pk = pack4(a[0] * LOG2E, a[1] * LOG2E,
                                        a[2] * LOG2E, a[3] * LOG2E);
                        *(int2*)((short*)Qg +
                            (((size_t)n * 8 + s) * HW + p) * 16 + quad * 4) = pk;
                    } else {       // K
                        int2 pk = pack4(a[0], a[1], a[2], a[3]);
                        *(int2*)((short*)Kg +
                            (((size_t)n * 8 + (s - 8)) * HW + p) * 16 + quad * 4) = pk;
                    }
                }
            } else {               // V: swapped operands -> C[p][o], channel-first store
                #pragma unroll
                for (int kc = 0; kc < 4; ++kc) {
                    frag8 wf = *(const frag8*)&wp[kc * 32];
                    a = __builtin_amdgcn_mfma_f32_16x16x32_bf16(bq[kc], wf, a, 0, 0, 0);
                }
                int ov = (s - 16) * 16 + l16;
                int p4 = pb + pq * 16 + quad * 4;
                if (p4 < HW) {
                    int2 pk = pack4(a[0], a[1], a[2], a[3]);
                    *(int2*)((short*)Vcf + ((size_t)n * CH + ov) * HW + p4) = pk;
                }
            }
        }
    }
}

// ---------------- k_go: fused gates + out-proj, 1024 threads, 32p per block ----------
__global__ __launch_bounds__(1024) void k_go(const bf16* __restrict__ Zb,
                                             const bf16* __restrict__ Ab,
                                             const bf16* __restrict__ Wg,
                                             const float* __restrict__ biasg,
                                             const bf16* __restrict__ Wout,
                                             const float* __restrict__ biaso,
                                             void* __restrict__ out,
                                             const void* __restrict__ wraw) {
    __shared__ short Hl[32][132];
    const int tid = threadIdx.x, w = tid >> 6, lane = tid & 63;
    const int quad = lane >> 4, l16 = lane & 15;
    const int n = blockIdx.x;
    const int pb = blockIdx.y * 32;
    const int f32f = detect_f32(wraw);
    frag8 zf = {0, 0, 0, 0, 0, 0, 0, 0};

    // ---- gates phase: wave = 16o x 16p, 16 waves cover 128o x 32p ----
    {
        const int obase = (w & 7) * 16, pl0 = (w >> 3) * 16;
        const int p1 = pb + pl0 + l16;
        const bool ok = p1 < HW;
        f32x4 acc[3];
        #pragma unroll
        for (int g = 0; g < 3; ++g) acc[g] = (f32x4){0.f, 0.f, 0.f, 0.f};
        #pragma unroll
        for (int kc = 0; kc < 8; ++kc) {
            const bf16* src = (kc < 4) ? Zb : Ab;
            int ko = (kc & 3) * 32 + quad * 8;
            frag8 bf1 = zf;
            if (ok) bf1 = *(const frag8*)&src[((size_t)n * HW + p1) * CH + ko];
            #pragma unroll
            for (int g = 0; g < 3; ++g) {
                frag8 wf = *(const frag8*)&Wg[g * 32768 + (obase + l16) * 256 +
                                              kc * 32 + quad * 8];
                acc[g] = __builtin_amdgcn_mfma_f32_16x16x32_bf16(wf, bf1, acc[g], 0, 0, 0);
            }
        }
        int og = obase + quad * 4;
        int2 hpk = {0, 0};
        if (ok) {
            float hv[4];
            #pragma unroll
            for (int r = 0; r < 4; ++r) {
                int o = og + r;
                float iv = fsigm(acc[0][r] + biasg[o]);
                float gv = ftanh(acc[1][r] + biasg[128 + o]);
                float ov = fsigm(acc[2][r] + biasg[256 + o]);
                hv[r] = ov * ftanh(iv * gv);
            }
            hpk = pack4(hv[0], hv[1], hv[2], hv[3]);
        }
        *(int2*)&Hl[pl0 + l16][og] = hpk;
    }
    __syncthreads();

    // ---- out-proj phase: wave (pq = w&1, os = w>>1) = 16o' x 16p ----
    {
        const int pq = w & 1, os = w >> 1;
        f32x4 acc = {0.f, 0.f, 0.f, 0.f};
        #pragma unroll
        for (int kc = 0; kc < 4; ++kc) {
            frag8 af = *(const frag8*)&Hl[pq * 16 + l16][kc * 32 + quad * 8];
            frag8 b0 = *(const frag8*)&Wout[(os * 16 + l16) * CH + kc * 32 + quad * 8];
            acc = __builtin_amdgcn_mfma_f32_16x16x32_bf16(af, b0, acc, 0, 0, 0);
        }
        int p4 = pb + pq * 16 + quad * 4;
        int o = os * 16 + l16;
        if (p4 < HW) {
            float bv = biaso[o];
            size_t di = ((size_t)n * CH + o) * HW + p4;
            if (f32f) {
                float4 fv = {acc[0] + bv, acc[1] + bv, acc[2] + bv, acc[3] + bv};
                *(float4*)&((float*)out)[di] = fv;
            } else {
                int2 pk = pack4(acc[0] + bv, acc[1] + bv, acc[2] + bv, acc[3] + bv);
                *(int2*)&((short*)out)[di] = pk;
            }
        }
    }
}

// ---------------- MFMA flash attention v6: 4-way d-split + VALU diet ----------------
// Q pre-scaled by LOG2E => exp2 (no per-score mul); tail handled out-of-loop (only its
// one valid 16-d tile computed, rest zeroed once). grid (8 n, 21 qtile, 8 head).
__global__ __launch_bounds__(1024) void k_attn(const bf16* __restrict__ Qg,
                                               const bf16* __restrict__ Kg,
                                               const bf16* __restrict__ Vcf,
                                               bf16* __restrict__ A) {
    __shared__ __align__(16) short Pl[16][16][72];
    __shared__ float Ocomb[3][4][16][17];
    __shared__ float Lcomb[3][4][16];

    const int tid = threadIdx.x;
    const int w = tid >> 6, lane = tid & 63;
    const int quad = lane >> 4, l16 = lane & 15;
    const int qw = w & 3, dq = w >> 2;
    const int n = blockIdx.x;
    const int qb = blockIdx.y * 64;
    const int head = blockIdx.z;
    const short* Qh = (const short*)Qg + ((size_t)(n * 8 + head)) * HW * 16;
    const short* Kh = (const short*)Kg + ((size_t)(n * 8 + head)) * HW * 16;
    const short* Vh = (const short*)Vcf + ((size_t)n * CH + head * 16) * HW;

    frag8 zf = {0, 0, 0, 0, 0, 0, 0, 0};
    frag8 qf = zf;
    const int qtok = qb + qw * 16 + l16;
    if (quad < 2 && qtok < HW)
        qf = *(const frag8*)&Qh[(size_t)qtok * 16 + quad * 8];

    f32x4 Oacc = {0.f, 0.f, 0.f, 0.f};
    float lsum = 0.0f;
    short* plrow = &Pl[w][l16][0];

    // main chunks (no masking): dq=0 -> ci 0..5, dq=1 -> 6..10, dq=2 -> 11..15,
    // dq=3 -> 16..19 (+ tail 20 below)
    const int cstart = dq ? (1 + 5 * dq) : 0;
    const int cmain = (dq == 3) ? 20 : (6 + 5 * dq);
    for (int ci = cstart; ci < cmain; ++ci) {
        int d0 = ci * 64;
        f32x4 ST[4];
        #pragma unroll
        for (int t = 0; t < 4; ++t) {
            frag8 kf = zf;
            if (quad < 2)
                kf = *(const frag8*)&Kh[(size_t)(d0 + t * 16 + l16) * 16 + quad * 8];
            f32x4 zacc = {0.f, 0.f, 0.f, 0.f};
            ST[t] = __builtin_amdgcn_mfma_f32_16x16x32_bf16(kf, qf, zacc, 0, 0, 0);
        }
        #pragma unroll
        for (int t = 0; t < 4; ++t) {
            float pf0 = exp2f(ST[t][0]);
            float pf1 = exp2f(ST[t][1]);
            float pf2 = exp2f(ST[t][2]);
            float pf3 = exp2f(ST[t][3]);
            lsum += (pf0 + pf1) + (pf2 + pf3);
            *(int2*)&plrow[t * 16 + quad * 4] = pack4(pf0, pf1, pf2, pf3);
        }
        #pragma unroll
        for (int s = 0; s < 2; ++s) {
            frag8 vf = *(const frag8*)&Vh[(size_t)l16 * HW + d0 + s * 32 + quad * 8];
            frag8 pf = *(const frag8*)&plrow[s * 32 + quad * 8];
            Oacc = __builtin_amdgcn_mfma_f32_16x16x32_bf16(vf, pf, Oacc, 0, 0, 0);
        }
    }
    if (dq == 3) {   // tail chunk d0=1280: only d 1280..1295 valid (t=0 tile)
        const int d0 = 1280;
        frag8 kf = zf;
        if (quad < 2)
            kf = *(const frag8*)&Kh[(size_t)(d0 + l16) * 16 + quad * 8];
        f32x4 zacc = {0.f, 0.f, 0.f, 0.f};
        f32x4 ST0 = __builtin_amdgcn_mfma_f32_16x16x32_bf16(kf, qf, zacc, 0, 0, 0);
        float pf0 = exp2f(ST0[0]);
        float pf1 = exp2f(ST0[1]);
        float pf2 = exp2f(ST0[2]);
        float pf3 = exp2f(ST0[3]);
        lsum += (pf0 + pf1) + (pf2 + pf3);
        *(int2*)&plrow[quad * 4] = pack4(pf0, pf1, pf2, pf3);
        int2 z2 = {0, 0};
        *(int2*)&plrow[16 + quad * 4] = z2;
        *(int2*)&plrow[32 + quad * 4] = z2;
        *(int2*)&plrow[48 + quad * 4] = z2;
        #pragma unroll
        for (int s = 0; s < 2; ++s) {
            frag8 vf = *(const frag8*)&Vh[(size_t)l16 * HW + d0 + s * 32 + quad * 8];
            frag8 pf = *(const frag8*)&plrow[s * 32 + quad * 8];
            Oacc = __builtin_amdgcn_mfma_f32_16x16x32_bf16(vf, pf, Oacc, 0, 0, 0);
        }
    }

    lsum += __shfl_xor(lsum, 16);
    lsum += __shfl_xor(lsum, 32);

    if (dq > 0) {
        int slot = dq - 1;
        #pragma unroll
        for (int r = 0; r < 4; ++r)
            Ocomb[slot][qw][quad * 4 + r][l16] = Oacc[r];
        if (quad == 0) Lcomb[slot][qw][l16] = lsum;
    }
    __syncthreads();
    if (dq == 0) {
        #pragma unroll
        for (int s = 0; s < 3; ++s) {
            #pragma unroll
            for (int r = 0; r < 4; ++r)
                Oacc[r] += Ocomb[s][qw][quad * 4 + r][l16];
            lsum += Lcomb[s][qw][l16];
        }
        if (qtok < HW) {
            float inv = frcp(lsum);
            int2 pk = pack4(Oacc[0] * inv, Oacc[1] * inv, Oacc[2] * inv, Oacc[3] * inv);
            short* An = (short*)A + (size_t)n * HW * CH;
            *(int2*)&An[(size_t)qtok * CH + head * 16 + quad * 4] = pk;
        }
    }
}

extern "C" void kernel_launch(void* const* d_in, const int* in_sizes, int n_in,
                              void* d_out, int out_size, void* d_ws, size_t ws_size,
                              hipStream_t stream) {
    char* ws = (char*)d_ws;
    bf16*  Wst  = (bf16*)(ws + 256);          // 327680 bf16
    float* Bst  = (float*)(ws + 655616);      // 768 f32
    bf16*  XT   = (bf16*)(ws + 1048576);      // channel-last [n][1296][128]
    bf16*  Zb   = XT + TT;
    bf16*  Qb   = Zb + TT;                    // head-grouped [n][8][1296][16]
    bf16*  Kb   = Qb + TT;
    bf16*  Vb   = Kb + TT;                    // channel-first [n][128][1296]
    bf16*  Ab   = Vb + TT;                    // ~17 MB total

    k_prep<<<1284, 256, 0, stream>>>(d_in[1], d_in[3], d_in[5], d_in[6], d_in[7],
                                     d_in[8], d_in[12], d_in[14], d_in[16],
                                     d_in[2], d_in[4], d_in[9], d_in[13], d_in[15], d_in[17],
                                     Wst, Bst);
    // n on blockIdx.x (gridDim.x == 8): per-batch XCD locality
    k_inm<<<dim3(8, 41, 4), 256, 0, stream>>>(d_in[0], d_in[1], Wst, Bst, XT);
    k_cq <<<dim3(8, 41), 1024, 0, stream>>>(XT, Wst + 16384, Wst + 163840, Bst + 128,
                                            Zb, Qb, Kb, Vb);
    k_attn<<<dim3(8, 21, 8), 1024, 0, stream>>>(Qb, Kb, Vb, Ab);
    k_go <<<dim3(8, 41), 1024, 0, stream>>>(Zb, Ab, Wst + 212992, Bst + 256,
                                            Wst + 311296, Bst + 640, d_out, d_in[1]);
}

// Round 16
// 218.721 us; speedup vs baseline: 1.1601x; 1.1601x over previous
//
#include <hip/hip_runtime.h>
#include <hip/hip_bf16.h>
#include <math.h>

typedef __hip_bfloat16 bf16;
typedef __attribute__((ext_vector_type(8))) short frag8;
typedef __attribute__((ext_vector_type(4))) float f32x4;

#define HW  1296
#define CH  128
#define TT  1327104   // 8 * 1296 * 128
#define LOG2E 1.4426950408889634f

__device__ __forceinline__ float b2f(bf16 v) { return __bfloat162float(v); }
__device__ __forceinline__ float bits2f(unsigned short u) {
    return __uint_as_float(((unsigned)u) << 16);
}
__device__ __forceinline__ float frcp(float x) { return __builtin_amdgcn_rcpf(x); }
__device__ __forceinline__ float fsigm(float x) { return frcp(1.0f + __expf(-x)); }
__device__ __forceinline__ float ftanh(float x) {
    float xc = fminf(15.0f, fmaxf(-15.0f, x));
    float e = __expf(2.0f * xc);
    return (e - 1.0f) * frcp(e + 1.0f);
}
// round-half-up f32->bf16 pair pack: 2 adds + 1 v_perm
__device__ __forceinline__ int packrh(float a, float b) {
    unsigned ua = __float_as_uint(a) + 0x8000u;
    unsigned ub = __float_as_uint(b) + 0x8000u;
    return (int)__builtin_amdgcn_perm(ub, ua, 0x07060302);
}
__device__ __forceinline__ int2 pack4(float a, float b, float c, float d) {
    int2 r; r.x = packrh(a, b); r.y = packrh(c, d); return r;
}

// inline wave-uniform dtype detection (256 probe elems of w_in)
__device__ __forceinline__ int detect_f32(const void* w) {
    const short4* p = (const short4*)w;
    short4 v = p[threadIdx.x & 63];
    int bad = 0;
    #pragma unroll
    for (int j = 0; j < 4; ++j) {
        float f = bits2f(((const unsigned short*)&v)[j]);
        if (!(fabsf(f) <= 100.0f)) bad = 1;
    }
    return __any(bad) ? 1 : 0;
}

// ---------------- weight prep ----------------
// Wst (bf16): w_in[128o][128i]@0 | wconvT[9tap][128o][128r]@16384 |
//   wqkv[384o][128i]@163840 | wg[3][128o][256k]@212992 | wout[128o][128i]@311296
// Bst f32[768]: in@0 conv@128 i@256 g@384 o@512 out@640
__global__ __launch_bounds__(256) void k_prep(
    const void* w_in, const void* w_conv, const void* wq, const void* wk, const void* wv,
    const void* w_i, const void* w_g, const void* w_o, const void* w_out,
    const void* b_in, const void* b_conv, const void* b_i, const void* b_g,
    const void* b_o, const void* b_out,
    bf16* __restrict__ Wdst, float* __restrict__ Bdst)
{
    int idx = blockIdx.x * 256 + threadIdx.x;
    const int f = detect_f32(w_in);
    if (idx < 327680) {
        const void* src; int si;
        if (idx < 16384)       { src = w_in; si = idx; }
        else if (idx < 163840) { int j = idx - 16384; int tap = j >> 14, rem = j & 16383;
                                 int o = rem >> 7, r = rem & 127;
                                 src = w_conv; si = o * 2304 + r * 9 + tap; }
        else if (idx < 212992) { int j = idx - 163840; int o = j >> 7, i = j & 127;
                                 int ws_ = o >> 7;
                                 src = ws_ == 0 ? wq : ws_ == 1 ? wk : wv;
                                 si = (o & 127) * 128 + i; }
        else if (idx < 311296) { int j = idx - 212992; int g = j >> 15, rem = j & 32767;
                                 int o = rem >> 8, k = rem & 255;
                                 src = g == 0 ? w_i : g == 1 ? w_g : w_o; si = o * 256 + k; }
        else                   { int j = idx - 311296; int o = j >> 7, i = j & 127;
                                 src = w_out; si = o * 128 + i; }
        float v = f ? ((const float*)src)[si] : b2f(((const bf16*)src)[si]);
        Wdst[idx] = __float2bfloat16(v);
    } else if (idx < 327680 + 768) {
        int j = idx - 327680; int b = j >> 7, e = j & 127;
        const void* src = b == 0 ? b_in : b == 1 ? b_conv : b == 2 ? b_i
                        : b == 3 ? b_g : b == 4 ? b_o : b_out;
        Bdst[j] = f ? ((const float*)src)[e] : b2f(((const bf16*)src)[e]);
    }
}

// ---------------- k_inm: fused transpose + MFMA GEMM + tanh ----------------
__global__ __launch_bounds__(256) void k_inm(const void* __restrict__ x,
                                             const void* __restrict__ wraw,
                                             const bf16* __restrict__ Wm,
                                             const float* __restrict__ bias,
                                             bf16* __restrict__ XT) {
    __shared__ short Xl[32][132];
    const int tid = threadIdx.x, wave = tid >> 6, lane = tid & 63;
    const int quad = lane >> 4, l16 = lane & 15;
    const int n = blockIdx.x;
    const int pbase = blockIdx.y * 32;
    const int obase = blockIdx.z * 32 + (wave & 1) * 16;
    const int pstrip = (wave >> 1) * 16;
    const int f = detect_f32(wraw);

    #pragma unroll
    for (int rep = 0; rep < 4; ++rep) {
        int u = tid + rep * 256;
        int i = u >> 3;
        int p4 = (u & 7) * 4;
        int p = pbase + p4;
        short4 s = {0, 0, 0, 0};
        if (p < HW) {
            size_t gi = (size_t)n * CH * HW + (size_t)i * HW + p;
            if (f) {
                float4 fv = *(const float4*)((const float*)x + gi);
                int2 pk = pack4(fv.x, fv.y, fv.z, fv.w);
                s = *(short4*)&pk;
            } else {
                s = *(const short4*)((const bf16*)x + gi);
            }
        }
        Xl[p4 + 0][i] = s.x; Xl[p4 + 1][i] = s.y;
        Xl[p4 + 2][i] = s.z; Xl[p4 + 3][i] = s.w;
    }
    __syncthreads();

    const int pl = pstrip + l16;
    f32x4 acc = {0.f, 0.f, 0.f, 0.f};
    #pragma unroll
    for (int kc = 0; kc < 4; ++kc) {
        int k = kc * 32 + quad * 8;
        short4 b0 = *(const short4*)&Xl[pl][k];
        short4 b1 = *(const short4*)&Xl[pl][k + 4];
        frag8 bf = {b0.x, b0.y, b0.z, b0.w, b1.x, b1.y, b1.z, b1.w};
        frag8 wf = *(const frag8*)&Wm[(obase + l16) * CH + k];
        acc = __builtin_amdgcn_mfma_f32_16x16x32_bf16(wf, bf, acc, 0, 0, 0);
    }

    int p = pbase + pstrip + l16;
    if (p < HW) {
        int og = obase + quad * 4;
        int2 pk = pack4(ftanh(acc[0] + bias[og + 0]), ftanh(acc[1] + bias[og + 1]),
                        ftanh(acc[2] + bias[og + 2]), ftanh(acc[3] + bias[og + 3]));
        *(int2*)((short*)XT + ((size_t)n * HW + p) * CH + og) = pk;
    }
}

// ---------------- MFMA GEMM family, 64p x 32o blocks (wave = 16o x 32p, 2 p-frags) ------
// MODE 0: CONV (9 taps, unrolled)  MODE 1: QKV (Q scaled by LOG2E, head-grouped; K
//   head-grouped; V channel-first via swap)  MODE 2: GATES (K=256, fused cell)
template<int MODE>
__global__ __launch_bounds__(256) void k_mm(
    const bf16* __restrict__ Act, const bf16* __restrict__ Act2,
    const bf16* __restrict__ Wm, const float* __restrict__ bias,
    bf16* __restrict__ o0, bf16* __restrict__ o1, bf16* __restrict__ o2)
{
    constexpr int NW  = (MODE == 2) ? 3 : 1;
    constexpr int KW  = (MODE == 2) ? 256 : 128;
    const int tid = threadIdx.x, wave = tid >> 6, lane = tid & 63;
    const int quad = lane >> 4, l16 = lane & 15;
    const int ostrip = wave & 1, pstrip = wave >> 1;
    const int n = blockIdx.x;
    const int obase = blockIdx.z * 32 + ostrip * 16;
    const int pbase = blockIdx.y * 64 + pstrip * 32;
    const bf16* actn = Act + (size_t)n * HW * CH;
    const bool vtile = (MODE == 1) && (obase >= 256);   // wave-uniform

    const int p1 = pbase + l16, p2 = pbase + 16 + l16;
    const bool p1ok = p1 < HW, p2ok = p2 < HW;

    frag8 zf = {0, 0, 0, 0, 0, 0, 0, 0};
    f32x4 acc[NW][2];
    #pragma unroll
    for (int g = 0; g < NW; ++g) {
        acc[g][0] = (f32x4){0.f, 0.f, 0.f, 0.f};
        acc[g][1] = (f32x4){0.f, 0.f, 0.f, 0.f};
    }

    if (MODE == 0) {
        const int h1 = p1 / 36, w1 = p1 - h1 * 36;
        const int h2 = p2 / 36, w2 = p2 - h2 * 36;
        #pragma unroll
        for (int tap = 0; tap < 9; ++tap) {
            int dy = tap / 3 - 1, dx = tap - (tap / 3) * 3 - 1;
            bool ok1 = p1ok && (unsigned)(h1 + dy) < 36u && (unsigned)(w1 + dx) < 36u;
            bool ok2 = p2ok && (unsigned)(h2 + dy) < 36u && (unsigned)(w2 + dx) < 36u;
            int sh = dy * 36 + dx;
            const bf16* a1 = actn + (size_t)(p1 + sh) * CH + quad * 8;
            const bf16* a2 = actn + (size_t)(p2 + sh) * CH + quad * 8;
            const bf16* wp = Wm + tap * 16384 + (obase + l16) * CH + quad * 8;
            #pragma unroll
            for (int kc = 0; kc < 4; ++kc) {
                frag8 bf1 = zf, bf2 = zf;
                if (ok1) bf1 = *(const frag8*)&a1[kc * 32];
                if (ok2) bf2 = *(const frag8*)&a2[kc * 32];
                frag8 wf = *(const frag8*)&wp[kc * 32];
                acc[0][0] = __builtin_amdgcn_mfma_f32_16x16x32_bf16(wf, bf1, acc[0][0], 0, 0, 0);
                acc[0][1] = __builtin_amdgcn_mfma_f32_16x16x32_bf16(wf, bf2, acc[0][1], 0, 0, 0);
            }
        }
    } else {
        const bf16* act2n = (MODE == 2) ? Act2 + (size_t)n * HW * CH : nullptr;
        #pragma unroll
        for (int kc = 0; kc < KW / 32; ++kc) {
            const bf16* src = (MODE == 2 && kc >= 4) ? act2n : actn;
            int ko = (MODE == 2 ? (kc & 3) : kc) * 32 + quad * 8;
            frag8 bf1 = zf, bf2 = zf;
            if (p1ok) bf1 = *(const frag8*)&src[(size_t)p1 * CH + ko];
            if (p2ok) bf2 = *(const frag8*)&src[(size_t)p2 * CH + ko];
            #pragma unroll
            for (int g = 0; g < NW; ++g) {
                const bf16* wp = Wm + g * 32768 + (obase + l16) * KW + kc * 32 + quad * 8;
                frag8 wf = *(const frag8*)wp;
                if (vtile) {
                    acc[g][0] = __builtin_amdgcn_mfma_f32_16x16x32_bf16(bf1, wf, acc[g][0], 0, 0, 0);
                    acc[g][1] = __builtin_amdgcn_mfma_f32_16x16x32_bf16(bf2, wf, acc[g][1], 0, 0, 0);
                } else {
                    acc[g][0] = __builtin_amdgcn_mfma_f32_16x16x32_bf16(wf, bf1, acc[g][0], 0, 0, 0);
                    acc[g][1] = __builtin_amdgcn_mfma_f32_16x16x32_bf16(wf, bf2, acc[g][1], 0, 0, 0);
                }
            }
        }
    }

    // ---- epilogue ----
    if (vtile) {
        int ov = (obase - 256) + l16;
        #pragma unroll
        for (int pt = 0; pt < 2; ++pt) {
            int p4 = pbase + pt * 16 + quad * 4;
            if (p4 >= HW) continue;
            int2 pk = pack4(acc[0][pt][0], acc[0][pt][1], acc[0][pt][2], acc[0][pt][3]);
            *(int2*)((short*)o2 + ((size_t)n * CH + ov) * HW + p4) = pk;
        }
        return;
    }
    const int og = obase + quad * 4;
    #pragma unroll
    for (int pt = 0; pt < 2; ++pt) {
        int p = pbase + pt * 16 + l16;
        if (p >= HW) continue;
        size_t rowoff = ((size_t)n * HW + p) * CH;
        if (MODE == 0) {
            int2 pk = pack4(acc[0][pt][0] + bias[og + 0], acc[0][pt][1] + bias[og + 1],
                            acc[0][pt][2] + bias[og + 2], acc[0][pt][3] + bias[og + 3]);
            *(int2*)((short*)o0 + rowoff + og) = pk;
        } else if (MODE == 1) {
            int which = og >> 7, ol = og & 127;
            size_t di = (((size_t)n * 8 + (ol >> 4)) * HW + p) * 16 + (ol & 15);
            if (which == 0) {   // Q: pre-scale by LOG2E for exp2 softmax
                int2 pk = pack4(acc[0][pt][0] * LOG2E, acc[0][pt][1] * LOG2E,
                                acc[0][pt][2] * LOG2E, acc[0][pt][3] * LOG2E);
                *(int2*)((short*)o0 + di) = pk;
            } else {            // K
                int2 pk = pack4(acc[0][pt][0], acc[0][pt][1], acc[0][pt][2], acc[0][pt][3]);
                *(int2*)((short*)o1 + di) = pk;
            }
        } else {
            float hv[4];
            #pragma unroll
            for (int r = 0; r < 4; ++r) {
                int o = og + r;
                float iv = fsigm(acc[0][pt][r] + bias[o]);
                float gv = ftanh(acc[1][pt][r] + bias[128 + o]);
                float ov = fsigm(acc[2][pt][r] + bias[256 + o]);
                hv[r] = ov * ftanh(iv * gv);
            }
            int2 pk = pack4(hv[0], hv[1], hv[2], hv[3]);
            *(int2*)((short*)o0 + rowoff + og) = pk;
        }
    }
}

// ---------------- k_outm: out[n][o][p] = W_out h + b (channel-first store) ----------------
__global__ __launch_bounds__(256) void k_outm(const bf16* __restrict__ Hb,
                                              const bf16* __restrict__ Wm,
                                              const float* __restrict__ bias,
                                              void* __restrict__ out,
                                              const void* __restrict__ wraw) {
    const int tid = threadIdx.x, wave = tid >> 6, lane = tid & 63;
    const int quad = lane >> 4, l16 = lane & 15;
    const int pstrip = wave & 1, ostrip = wave >> 1;
    const int n = blockIdx.x;
    const int pbase = blockIdx.y * 32 + pstrip * 16;
    const int obase = blockIdx.z * 64 + ostrip * 32;
    if (pbase >= HW) return;
    const int f32f = detect_f32(wraw);
    const bf16* hn = Hb + (size_t)n * HW * CH;
    const int pa = pbase + l16;

    f32x4 acc0 = {0.f, 0.f, 0.f, 0.f}, acc1 = {0.f, 0.f, 0.f, 0.f};
    #pragma unroll
    for (int kc = 0; kc < 4; ++kc) {
        int ko = kc * 32 + quad * 8;
        frag8 af = *(const frag8*)&hn[(size_t)pa * CH + ko];
        frag8 b0 = *(const frag8*)&Wm[(obase + l16) * CH + ko];
        frag8 b1 = *(const frag8*)&Wm[(obase + 16 + l16) * CH + ko];
        acc0 = __builtin_amdgcn_mfma_f32_16x16x32_bf16(af, b0, acc0, 0, 0, 0);
        acc1 = __builtin_amdgcn_mfma_f32_16x16x32_bf16(af, b1, acc1, 0, 0, 0);
    }
    int p4 = pbase + quad * 4;
    #pragma unroll
    for (int ot = 0; ot < 2; ++ot) {
        int o = obase + ot * 16 + l16;
        f32x4 a = ot ? acc1 : acc0;
        float bv = bias[o];
        size_t di = ((size_t)n * CH + o) * HW + p4;
        if (f32f) {
            float4 fv = {a[0] + bv, a[1] + bv, a[2] + bv, a[3] + bv};
            *(float4*)&((float*)out)[di] = fv;
        } else {
            int2 pk = pack4(a[0] + bv, a[1] + bv, a[2] + bv, a[3] + bv);
            *(int2*)&((short*)out)[di] = pk;
        }
    }
}

// ---------------- MFMA flash attention v6: 4-way d-split + exp2 + hoisted tail --------
// Q pre-scaled by LOG2E in k_mm<1>. Main chunks mask-free; tail (d0=1280) computed
// once with its single valid 16-d tile. grid (8 n, 21 qtile, 8 head).
__global__ __launch_bounds__(1024) void k_attn(const bf16* __restrict__ Qg,
                                               const bf16* __restrict__ Kg,
                                               const bf16* __restrict__ Vcf,
                                               bf16* __restrict__ A) {
    __shared__ __align__(16) short Pl[16][16][72];
    __shared__ float Ocomb[3][4][16][17];
    __shared__ float Lcomb[3][4][16];

    const int tid = threadIdx.x;
    const int w = tid >> 6, lane = tid & 63;
    const int quad = lane >> 4, l16 = lane & 15;
    const int qw = w & 3, dq = w >> 2;
    const int n = blockIdx.x;
    const int qb = blockIdx.y * 64;
    const int head = blockIdx.z;
    const short* Qh = (const short*)Qg + ((size_t)(n * 8 + head)) * HW * 16;
    const short* Kh = (const short*)Kg + ((size_t)(n * 8 + head)) * HW * 16;
    const short* Vh = (const short*)Vcf + ((size_t)n * CH + head * 16) * HW;

    frag8 zf = {0, 0, 0, 0, 0, 0, 0, 0};
    frag8 qf = zf;
    const int qtok = qb + qw * 16 + l16;
    if (quad < 2 && qtok < HW)
        qf = *(const frag8*)&Qh[(size_t)qtok * 16 + quad * 8];

    f32x4 Oacc = {0.f, 0.f, 0.f, 0.f};
    float lsum = 0.0f;
    short* plrow = &Pl[w][l16][0];

    const int cstart = dq ? (1 + 5 * dq) : 0;   // {0,6,11,16}
    const int cmain = (dq == 3) ? 20 : (6 + 5 * dq);
    for (int ci = cstart; ci < cmain; ++ci) {
        int d0 = ci * 64;
        f32x4 ST[4];
        #pragma unroll
        for (int t = 0; t < 4; ++t) {
            frag8 kf = zf;
            if (quad < 2)
                kf = *(const frag8*)&Kh[(size_t)(d0 + t * 16 + l16) * 16 + quad * 8];
            f32x4 zacc = {0.f, 0.f, 0.f, 0.f};
            ST[t] = __builtin_amdgcn_mfma_f32_16x16x32_bf16(kf, qf, zacc, 0, 0, 0);
        }
        #pragma unroll
        for (int t = 0; t < 4; ++t) {
            float pf0 = exp2f(ST[t][0]);
            float pf1 = exp2f(ST[t][1]);
            float pf2 = exp2f(ST[t][2]);
            float pf3 = exp2f(ST[t][3]);
            lsum += (pf0 + pf1) + (pf2 + pf3);
            *(int2*)&plrow[t * 16 + quad * 4] = pack4(pf0, pf1, pf2, pf3);
        }
        #pragma unroll
        for (int s = 0; s < 2; ++s) {
            frag8 vf = *(const frag8*)&Vh[(size_t)l16 * HW + d0 + s * 32 + quad * 8];
            frag8 pf = *(const frag8*)&plrow[s * 32 + quad * 8];
            Oacc = __builtin_amdgcn_mfma_f32_16x16x32_bf16(vf, pf, Oacc, 0, 0, 0);
        }
    }
    if (dq == 3) {   // tail d0=1280: only d 1280..1295 valid
        const int d0 = 1280;
        frag8 kf = zf;
        if (quad < 2)
            kf = *(const frag8*)&Kh[(size_t)(d0 + l16) * 16 + quad * 8];
        f32x4 zacc = {0.f, 0.f, 0.f, 0.f};
        f32x4 ST0 = __builtin_amdgcn_mfma_f32_16x16x32_bf16(kf, qf, zacc, 0, 0, 0);
        float pf0 = exp2f(ST0[0]);
        float pf1 = exp2f(ST0[1]);
        float pf2 = exp2f(ST0[2]);
        float pf3 = exp2f(ST0[3]);
        lsum += (pf0 + pf1) + (pf2 + pf3);
        *(int2*)&plrow[quad * 4] = pack4(pf0, pf1, pf2, pf3);
        int2 z2 = {0, 0};
        *(int2*)&plrow[16 + quad * 4] = z2;
        *(int2*)&plrow[32 + quad * 4] = z2;
        *(int2*)&plrow[48 + quad * 4] = z2;
        #pragma unroll
        for (int s = 0; s < 2; ++s) {
            frag8 vf = *(const frag8*)&Vh[(size_t)l16 * HW + d0 + s * 32 + quad * 8];
            frag8 pf = *(const frag8*)&plrow[s * 32 + quad * 8];
            Oacc = __builtin_amdgcn_mfma_f32_16x16x32_bf16(vf, pf, Oacc, 0, 0, 0);
        }
    }

    lsum += __shfl_xor(lsum, 16);
    lsum += __shfl_xor(lsum, 32);

    if (dq > 0) {
        int slot = dq - 1;
        #pragma unroll
        for (int r = 0; r < 4; ++r)
            Ocomb[slot][qw][quad * 4 + r][l16] = Oacc[r];
        if (quad == 0) Lcomb[slot][qw][l16] = lsum;
    }
    __syncthreads();
    if (dq == 0) {
        #pragma unroll
        for (int s = 0; s < 3; ++s) {
            #pragma unroll
            for (int r = 0; r < 4; ++r)
                Oacc[r] += Ocomb[s][qw][quad * 4 + r][l16];
            lsum += Lcomb[s][qw][l16];
        }
        if (qtok < HW) {
            float inv = frcp(lsum);
            int2 pk = pack4(Oacc[0] * inv, Oacc[1] * inv, Oacc[2] * inv, Oacc[3] * inv);
            short* An = (short*)A + (size_t)n * HW * CH;
            *(int2*)&An[(size_t)qtok * CH + head * 16 + quad * 4] = pk;
        }
    }
}

extern "C" void kernel_launch(void* const* d_in, const int* in_sizes, int n_in,
                              void* d_out, int out_size, void* d_ws, size_t ws_size,
                              hipStream_t stream) {
    char* ws = (char*)d_ws;
    bf16*  Wst  = (bf16*)(ws + 256);          // 327680 bf16
    float* Bst  = (float*)(ws + 655616);      // 768 f32
    bf16*  XT   = (bf16*)(ws + 1048576);      // channel-last [n][1296][128]
    bf16*  Zb   = XT + TT;
    bf16*  Qb   = Zb + TT;                    // head-grouped [n][8][1296][16], LOG2E-scaled
    bf16*  Kb   = Qb + TT;                    // head-grouped
    bf16*  Vb   = Kb + TT;                    // channel-first [n][128][1296]
    bf16*  Ab   = Vb + TT;
    bf16*  Hb   = Ab + TT;                    // ~19.6 MB total

    k_prep<<<1284, 256, 0, stream>>>(d_in[1], d_in[3], d_in[5], d_in[6], d_in[7],
                                     d_in[8], d_in[12], d_in[14], d_in[16],
                                     d_in[2], d_in[4], d_in[9], d_in[13], d_in[15], d_in[17],
                                     Wst, Bst);
    // n on blockIdx.x (gridDim.x == 8): per-batch XCD locality
    k_inm<<<dim3(8, 41, 4), 256, 0, stream>>>(d_in[0], d_in[1], Wst, Bst, XT);
    k_mm<0><<<dim3(8, 21, 4), 256, 0, stream>>>(XT, nullptr, Wst + 16384, Bst + 128,
                                                Zb, nullptr, nullptr);
    k_mm<1><<<dim3(8, 21, 12), 256, 0, stream>>>(Zb, nullptr, Wst + 163840, nullptr,
                                                 Qb, Kb, Vb);
    k_attn<<<dim3(8, 21, 8), 1024, 0, stream>>>(Qb, Kb, Vb, Ab);
    k_mm<2><<<dim3(8, 21, 4), 256, 0, stream>>>(Zb, Ab, Wst + 212992, Bst + 256,
                                                Hb, nullptr, nullptr);
    k_outm<<<dim3(8, 41, 2), 256, 0, stream>>>(Hb, Wst + 311296, Bst + 640, d_out, d_in[1]);
}

// Round 17
// 218.513 us; speedup vs baseline: 1.1612x; 1.0010x over previous
//
#include <hip/hip_runtime.h>
#include <hip/hip_bf16.h>
#include <math.h>

typedef __hip_bfloat16 bf16;
typedef __attribute__((ext_vector_type(8))) short frag8;
typedef __attribute__((ext_vector_type(4))) float f32x4;

#define HW  1296
#define CH  128
#define TT  1327104   // 8 * 1296 * 128
#define LOG2E 1.4426950408889634f

__device__ __forceinline__ float b2f(bf16 v) { return __bfloat162float(v); }
__device__ __forceinline__ float bits2f(unsigned short u) {
    return __uint_as_float(((unsigned)u) << 16);
}
__device__ __forceinline__ float frcp(float x) { return __builtin_amdgcn_rcpf(x); }
__device__ __forceinline__ float fexp2(float x) { return __builtin_amdgcn_exp2f(x); }
__device__ __forceinline__ float fsigm(float x) { return frcp(1.0f + __expf(-x)); }
__device__ __forceinline__ float ftanh(float x) {
    float xc = fminf(15.0f, fmaxf(-15.0f, x));
    float e = __expf(2.0f * xc);
    return (e - 1.0f) * frcp(e + 1.0f);
}
// round-half-up f32->bf16 pair pack: 2 adds + 1 v_perm
__device__ __forceinline__ int packrh(float a, float b) {
    unsigned ua = __float_as_uint(a) + 0x8000u;
    unsigned ub = __float_as_uint(b) + 0x8000u;
    return (int)__builtin_amdgcn_perm(ub, ua, 0x07060302);
}
__device__ __forceinline__ int2 pack4(float a, float b, float c, float d) {
    int2 r; r.x = packrh(a, b); r.y = packrh(c, d); return r;
}

// inline wave-uniform dtype detection (256 probe elems of w_in)
__device__ __forceinline__ int detect_f32(const void* w) {
    const short4* p = (const short4*)w;
    short4 v = p[threadIdx.x & 63];
    int bad = 0;
    #pragma unroll
    for (int j = 0; j < 4; ++j) {
        float f = bits2f(((const unsigned short*)&v)[j]);
        if (!(fabsf(f) <= 100.0f)) bad = 1;
    }
    return __any(bad) ? 1 : 0;
}

// ---------------- weight prep ----------------
// Wst (bf16): w_in[128o][128i]@0 | wconvT[9tap][128o][128r]@16384 |
//   wqkv[384o][128i]@163840 | wg[3][128o][256k]@212992 | wout[128o][128i]@311296
// Bst f32[768]: in@0 conv@128 i@256 g@384 o@512 out@640
__global__ __launch_bounds__(256) void k_prep(
    const void* w_in, const void* w_conv, const void* wq, const void* wk, const void* wv,
    const void* w_i, const void* w_g, const void* w_o, const void* w_out,
    const void* b_in, const void* b_conv, const void* b_i, const void* b_g,
    const void* b_o, const void* b_out,
    bf16* __restrict__ Wdst, float* __restrict__ Bdst)
{
    int idx = blockIdx.x * 256 + threadIdx.x;
    const int f = detect_f32(w_in);
    if (idx < 327680) {
        const void* src; int si;
        if (idx < 16384)       { src = w_in; si = idx; }
        else if (idx < 163840) { int j = idx - 16384; int tap = j >> 14, rem = j & 16383;
                                 int o = rem >> 7, r = rem & 127;
                                 src = w_conv; si = o * 2304 + r * 9 + tap; }
        else if (idx < 212992) { int j = idx - 163840; int o = j >> 7, i = j & 127;
                                 int ws_ = o >> 7;
                                 src = ws_ == 0 ? wq : ws_ == 1 ? wk : wv;
                                 si = (o & 127) * 128 + i; }
        else if (idx < 311296) { int j = idx - 212992; int g = j >> 15, rem = j & 32767;
                                 int o = rem >> 8, k = rem & 255;
                                 src = g == 0 ? w_i : g == 1 ? w_g : w_o; si = o * 256 + k; }
        else                   { int j = idx - 311296; int o = j >> 7, i = j & 127;
                                 src = w_out; si = o * 128 + i; }
        float v = f ? ((const float*)src)[si] : b2f(((const bf16*)src)[si]);
        Wdst[idx] = __float2bfloat16(v);
    } else if (idx < 327680 + 768) {
        int j = idx - 327680; int b = j >> 7, e = j & 127;
        const void* src = b == 0 ? b_in : b == 1 ? b_conv : b == 2 ? b_i
                        : b == 3 ? b_g : b == 4 ? b_o : b_out;
        Bdst[j] = f ? ((const float*)src)[e] : b2f(((const bf16*)src)[e]);
    }
}

// ---------------- k_inm: fused transpose + MFMA GEMM + tanh ----------------
__global__ __launch_bounds__(256) void k_inm(const void* __restrict__ x,
                                             const void* __restrict__ wraw,
                                             const bf16* __restrict__ Wm,
                                             const float* __restrict__ bias,
                                             bf16* __restrict__ XT) {
    __shared__ short Xl[32][132];
    const int tid = threadIdx.x, wave = tid >> 6, lane = tid & 63;
    const int quad = lane >> 4, l16 = lane & 15;
    const int n = blockIdx.x;
    const int pbase = blockIdx.y * 32;
    const int obase = blockIdx.z * 32 + (wave & 1) * 16;
    const int pstrip = (wave >> 1) * 16;
    const int f = detect_f32(wraw);

    #pragma unroll
    for (int rep = 0; rep < 4; ++rep) {
        int u = tid + rep * 256;
        int i = u >> 3;
        int p4 = (u & 7) * 4;
        int p = pbase + p4;
        short4 s = {0, 0, 0, 0};
        if (p < HW) {
            size_t gi = (size_t)n * CH * HW + (size_t)i * HW + p;
            if (f) {
                float4 fv = *(const float4*)((const float*)x + gi);
                int2 pk = pack4(fv.x, fv.y, fv.z, fv.w);
                s = *(short4*)&pk;
            } else {
                s = *(const short4*)((const bf16*)x + gi);
            }
        }
        Xl[p4 + 0][i] = s.x; Xl[p4 + 1][i] = s.y;
        Xl[p4 + 2][i] = s.z; Xl[p4 + 3][i] = s.w;
    }
    __syncthreads();

    const int pl = pstrip + l16;
    f32x4 acc = {0.f, 0.f, 0.f, 0.f};
    #pragma unroll
    for (int kc = 0; kc < 4; ++kc) {
        int k = kc * 32 + quad * 8;
        short4 b0 = *(const short4*)&Xl[pl][k];
        short4 b1 = *(const short4*)&Xl[pl][k + 4];
        frag8 bf = {b0.x, b0.y, b0.z, b0.w, b1.x, b1.y, b1.z, b1.w};
        frag8 wf = *(const frag8*)&Wm[(obase + l16) * CH + k];
        acc = __builtin_amdgcn_mfma_f32_16x16x32_bf16(wf, bf, acc, 0, 0, 0);
    }

    int p = pbase + pstrip + l16;
    if (p < HW) {
        int og = obase + quad * 4;
        int2 pk = pack4(ftanh(acc[0] + bias[og + 0]), ftanh(acc[1] + bias[og + 1]),
                        ftanh(acc[2] + bias[og + 2]), ftanh(acc[3] + bias[og + 3]));
        *(int2*)((short*)XT + ((size_t)n * HW + p) * CH + og) = pk;
    }
}

// ---------------- k_cq: fused conv3x3 + qkv, 512 threads, 32p x 128o per block --------
// conv phase: 8 waves, wave w = 16o x 32p (2 p-frags, r14-proven shape); z -> global+LDS
// qkv phase: wave w does 3 tasks s = w + j*8 (j=0 Q, 1 K, 2 V), B-frags from LDS z,
//   2 p-frags each. Q scaled by LOG2E head-grouped; K head-grouped; V channel-first
//   via swapped-operand MFMA.
__global__ __launch_bounds__(512) void k_cq(const bf16* __restrict__ XT,
                                            const bf16* __restrict__ Wconv,
                                            const bf16* __restrict__ Wqkv,
                                            const float* __restrict__ biasc,
                                            bf16* __restrict__ Zb,
                                            bf16* __restrict__ Qg,
                                            bf16* __restrict__ Kg,
                                            bf16* __restrict__ Vcf) {
    __shared__ short Zl[32][132];
    const int tid = threadIdx.x, w = tid >> 6, lane = tid & 63;
    const int quad = lane >> 4, l16 = lane & 15;
    const int n = blockIdx.x;
    const int pb = blockIdx.y * 32;
    const bf16* actn = XT + (size_t)n * HW * CH;
    frag8 zf = {0, 0, 0, 0, 0, 0, 0, 0};

    // ---- conv phase ----
    {
        const int obase = w * 16;
        const int p1 = pb + l16, p2 = pb + 16 + l16;
        const bool p1ok = p1 < HW, p2ok = p2 < HW;
        const int h1 = p1 / 36, w1 = p1 - h1 * 36;
        const int h2 = p2 / 36, w2 = p2 - h2 * 36;
        f32x4 acc0 = {0.f, 0.f, 0.f, 0.f}, acc1 = {0.f, 0.f, 0.f, 0.f};
        #pragma unroll
        for (int tap = 0; tap < 9; ++tap) {
            int dy = tap / 3 - 1, dx = tap - (tap / 3) * 3 - 1;
            bool ok1 = p1ok && (unsigned)(h1 + dy) < 36u && (unsigned)(w1 + dx) < 36u;
            bool ok2 = p2ok && (unsigned)(h2 + dy) < 36u && (unsigned)(w2 + dx) < 36u;
            int sh = dy * 36 + dx;
            const bf16* a1 = actn + (size_t)(p1 + sh) * CH + quad * 8;
            const bf16* a2 = actn + (size_t)(p2 + sh) * CH + quad * 8;
            const bf16* wp = Wconv + tap * 16384 + (obase + l16) * CH + quad * 8;
            #pragma unroll
            for (int kc = 0; kc < 4; ++kc) {
                frag8 bf1 = zf, bf2 = zf;
                if (ok1) bf1 = *(const frag8*)&a1[kc * 32];
                if (ok2) bf2 = *(const frag8*)&a2[kc * 32];
                frag8 wf = *(const frag8*)&wp[kc * 32];
                acc0 = __builtin_amdgcn_mfma_f32_16x16x32_bf16(wf, bf1, acc0, 0, 0, 0);
                acc1 = __builtin_amdgcn_mfma_f32_16x16x32_bf16(wf, bf2, acc1, 0, 0, 0);
            }
        }
        const int og = obase + quad * 4;
        #pragma unroll
        for (int pt = 0; pt < 2; ++pt) {
            int p = pb + pt * 16 + l16;
            f32x4 a = pt ? acc1 : acc0;
            int2 zpk = {0, 0};
            if (p < HW) {
                zpk = pack4(a[0] + biasc[og + 0], a[1] + biasc[og + 1],
                            a[2] + biasc[og + 2], a[3] + biasc[og + 3]);
                *(int2*)((short*)Zb + ((size_t)n * HW + p) * CH + og) = zpk;
            }
            *(int2*)&Zl[pt * 16 + l16][og] = zpk;
        }
    }
    __syncthreads();

    // ---- qkv phase ----
    {
        frag8 b1[4], b2[4];
        #pragma unroll
        for (int kc = 0; kc < 4; ++kc) {
            b1[kc] = *(const frag8*)&Zl[l16][kc * 32 + quad * 8];
            b2[kc] = *(const frag8*)&Zl[16 + l16][kc * 32 + quad * 8];
        }
        #pragma unroll
        for (int j = 0; j < 3; ++j) {
            const int s = w + j * 8;     // 0..7 Q, 8..15 K, 16..23 V
            const bf16* wp = Wqkv + (s * 16 + l16) * CH + quad * 8;
            f32x4 a0 = {0.f, 0.f, 0.f, 0.f}, a1 = {0.f, 0.f, 0.f, 0.f};
            if (j < 2) {
                #pragma unroll
                for (int kc = 0; kc < 4; ++kc) {
                    frag8 wf = *(const frag8*)&wp[kc * 32];
                    a0 = __builtin_amdgcn_mfma_f32_16x16x32_bf16(wf, b1[kc], a0, 0, 0, 0);
                    a1 = __builtin_amdgcn_mfma_f32_16x16x32_bf16(wf, b2[kc], a1, 0, 0, 0);
                }
                #pragma unroll
                for (int pt = 0; pt < 2; ++pt) {
                    int p = pb + pt * 16 + l16;
                    if (p >= HW) continue;
                    f32x4 a = pt ? a1 : a0;
                    size_t di = (((size_t)n * 8 + w) * HW + p) * 16 + quad * 4;
                    if (j == 0) {   // Q scaled by LOG2E
                        int2 pk = pack4(a[0] * LOG2E, a[1] * LOG2E,
                                        a[2] * LOG2E, a[3] * LOG2E);
                        *(int2*)((short*)Qg + di) = pk;
                    } else {        // K
                        int2 pk = pack4(a[0], a[1], a[2], a[3]);
                        *(int2*)((short*)Kg + di) = pk;
                    }
                }
            } else {                // V: swapped operands -> D[p][o], channel-first
                #pragma unroll
                for (int kc = 0; kc < 4; ++kc) {
                    frag8 wf = *(const frag8*)&wp[kc * 32];
                    a0 = __builtin_amdgcn_mfma_f32_16x16x32_bf16(b1[kc], wf, a0, 0, 0, 0);
                    a1 = __builtin_amdgcn_mfma_f32_16x16x32_bf16(b2[kc], wf, a1, 0, 0, 0);
                }
                int ov = w * 16 + l16;
                #pragma unroll
                for (int pt = 0; pt < 2; ++pt) {
                    int p4 = pb + pt * 16 + quad * 4;
                    if (p4 >= HW) continue;
                    f32x4 a = pt ? a1 : a0;
                    int2 pk = pack4(a[0], a[1], a[2], a[3]);
                    *(int2*)((short*)Vcf + ((size_t)n * CH + ov) * HW + p4) = pk;
                }
            }
        }
    }
}

// ---------------- k_go: fused gates + out-proj, 512 threads, 32p x 128o per block ------
// gates phase: 8 waves, wave w = 16o x 32p (2 p-frags, 3 gate mats); h -> LDS
// out phase: wave (pstrip = w&1, ostrip = w>>1) = 16p x 32o (2 W-streams)
__global__ __launch_bounds__(512) void k_go(const bf16* __restrict__ Zb,
                                            const bf16* __restrict__ Ab,
                                            const bf16* __restrict__ Wg,
                                            const float* __restrict__ biasg,
                                            const bf16* __restrict__ Wout,
                                            const float* __restrict__ biaso,
                                            void* __restrict__ out,
                                            const void* __restrict__ wraw) {
    __shared__ short Hl[32][132];
    const int tid = threadIdx.x, w = tid >> 6, lane = tid & 63;
    const int quad = lane >> 4, l16 = lane & 15;
    const int n = blockIdx.x;
    const int pb = blockIdx.y * 32;
    const int f32f = detect_f32(wraw);
    frag8 zf = {0, 0, 0, 0, 0, 0, 0, 0};

    // ---- gates phase ----
    {
        const int obase = w * 16;
        const int p1 = pb + l16, p2 = pb + 16 + l16;
        const bool p1ok = p1 < HW, p2ok = p2 < HW;
        f32x4 acc[3][2];
        #pragma unroll
        for (int g = 0; g < 3; ++g) {
            acc[g][0] = (f32x4){0.f, 0.f, 0.f, 0.f};
            acc[g][1] = (f32x4){0.f, 0.f, 0.f, 0.f};
        }
        #pragma unroll
        for (int kc = 0; kc < 8; ++kc) {
            const bf16* src = (kc < 4) ? Zb : Ab;
            int ko = (kc & 3) * 32 + quad * 8;
            frag8 bf1 = zf, bf2 = zf;
            if (p1ok) bf1 = *(const frag8*)&src[((size_t)n * HW + p1) * CH + ko];
            if (p2ok) bf2 = *(const frag8*)&src[((size_t)n * HW + p2) * CH + ko];
            #pragma unroll
            for (int g = 0; g < 3; ++g) {
                frag8 wf = *(const frag8*)&Wg[g * 32768 + (obase + l16) * 256 +
                                              kc * 32 + quad * 8];
                acc[g][0] = __builtin_amdgcn_mfma_f32_16x16x32_bf16(wf, bf1, acc[g][0], 0, 0, 0);
                acc[g][1] = __builtin_amdgcn_mfma_f32_16x16x32_bf16(wf, bf2, acc[g][1], 0, 0, 0);
            }
        }
        const int og = obase + quad * 4;
        #pragma unroll
        for (int pt = 0; pt < 2; ++pt) {
            int p = pb + pt * 16 + l16;
            int2 hpk = {0, 0};
            if (p < HW) {
                float hv[4];
                #pragma unroll
                for (int r = 0; r < 4; ++r) {
                    int o = og + r;
                    float iv = fsigm(acc[0][pt][r] + biasg[o]);
                    float gv = ftanh(acc[1][pt][r] + biasg[128 + o]);
                    float ov = fsigm(acc[2][pt][r] + biasg[256 + o]);
                    hv[r] = ov * ftanh(iv * gv);
                }
                hpk = pack4(hv[0], hv[1], hv[2], hv[3]);
            }
            *(int2*)&Hl[pt * 16 + l16][og] = hpk;
        }
    }
    __syncthreads();

    // ---- out-proj phase ----
    {
        const int pstrip = w & 1, ostrip = w >> 1;
        const int obase = ostrip * 32;
        const int pl = pstrip * 16 + l16;
        f32x4 acc0 = {0.f, 0.f, 0.f, 0.f}, acc1 = {0.f, 0.f, 0.f, 0.f};
        #pragma unroll
        for (int kc = 0; kc < 4; ++kc) {
            int ko = kc * 32 + quad * 8;
            frag8 af = *(const frag8*)&Hl[pl][ko];
            frag8 b0 = *(const frag8*)&Wout[(obase + l16) * CH + ko];
            frag8 b1 = *(const frag8*)&Wout[(obase + 16 + l16) * CH + ko];
            acc0 = __builtin_amdgcn_mfma_f32_16x16x32_bf16(af, b0, acc0, 0, 0, 0);
            acc1 = __builtin_amdgcn_mfma_f32_16x16x32_bf16(af, b1, acc1, 0, 0, 0);
        }
        int p4 = pb + pstrip * 16 + quad * 4;
        if (p4 < HW) {
            #pragma unroll
            for (int ot = 0; ot < 2; ++ot) {
                int o = obase + ot * 16 + l16;
                f32x4 a = ot ? acc1 : acc0;
                float bv = biaso[o];
                size_t di = ((size_t)n * CH + o) * HW + p4;
                if (f32f) {
                    float4 fv = {a[0] + bv, a[1] + bv, a[2] + bv, a[3] + bv};
                    *(float4*)&((float*)out)[di] = fv;
                } else {
                    int2 pk = pack4(a[0] + bv, a[1] + bv, a[2] + bv, a[3] + bv);
                    *(int2*)&((short*)out)[di] = pk;
                }
            }
        }
    }
}

// ---------------- MFMA flash attention v7: 4-way d-split, raw v_exp, hoisted tail ------
// Q pre-scaled by LOG2E => P = v_exp_f32(S) directly (1 inst/score).
// grid (8 n, 21 qtile, 8 head).
__global__ __launch_bounds__(1024) void k_attn(const bf16* __restrict__ Qg,
                                               const bf16* __restrict__ Kg,
                                               const bf16* __restrict__ Vcf,
                                               bf16* __restrict__ A) {
    __shared__ __align__(16) short Pl[16][16][72];
    __shared__ float Ocomb[3][4][16][17];
    __shared__ float Lcomb[3][4][16];

    const int tid = threadIdx.x;
    const int w = tid >> 6, lane = tid & 63;
    const int quad = lane >> 4, l16 = lane & 15;
    const int qw = w & 3, dq = w >> 2;
    const int n = blockIdx.x;
    const int qb = blockIdx.y * 64;
    const int head = blockIdx.z;
    const short* Qh = (const short*)Qg + ((size_t)(n * 8 + head)) * HW * 16;
    const short* Kh = (const short*)Kg + ((size_t)(n * 8 + head)) * HW * 16;
    const short* Vh = (const short*)Vcf + ((size_t)n * CH + head * 16) * HW;

    frag8 zf = {0, 0, 0, 0, 0, 0, 0, 0};
    frag8 qf = zf;
    const int qtok = qb + qw * 16 + l16;
    if (quad < 2 && qtok < HW)
        qf = *(const frag8*)&Qh[(size_t)qtok * 16 + quad * 8];

    f32x4 Oacc = {0.f, 0.f, 0.f, 0.f};
    float lsum = 0.0f;
    short* plrow = &Pl[w][l16][0];

    const int cstart = dq ? (1 + 5 * dq) : 0;   // {0,6,11,16}
    const int cmain = (dq == 3) ? 20 : (6 + 5 * dq);
    for (int ci = cstart; ci < cmain; ++ci) {
        int d0 = ci * 64;
        f32x4 ST[4];
        #pragma unroll
        for (int t = 0; t < 4; ++t) {
            frag8 kf = zf;
            if (quad < 2)
                kf = *(const frag8*)&Kh[(size_t)(d0 + t * 16 + l16) * 16 + quad * 8];
            f32x4 zacc = {0.f, 0.f, 0.f, 0.f};
            ST[t] = __builtin_amdgcn_mfma_f32_16x16x32_bf16(kf, qf, zacc, 0, 0, 0);
        }
        #pragma unroll
        for (int t = 0; t < 4; ++t) {
            float pf0 = fexp2(ST[t][0]);
            float pf1 = fexp2(ST[t][1]);
            float pf2 = fexp2(ST[t][2]);
            float pf3 = fexp2(ST[t][3]);
            lsum += (pf0 + pf1) + (pf2 + pf3);
            *(int2*)&plrow[t * 16 + quad * 4] = pack4(pf0, pf1, pf2, pf3);
        }
        #pragma unroll
        for (int s = 0; s < 2; ++s) {
            frag8 vf = *(const frag8*)&Vh[(size_t)l16 * HW + d0 + s * 32 + quad * 8];
            frag8 pf = *(const frag8*)&plrow[s * 32 + quad * 8];
            Oacc = __builtin_amdgcn_mfma_f32_16x16x32_bf16(vf, pf, Oacc, 0, 0, 0);
        }
    }
    if (dq == 3) {   // tail d0=1280: only d 1280..1295 valid
        const int d0 = 1280;
        frag8 kf = zf;
        if (quad < 2)
            kf = *(const frag8*)&Kh[(size_t)(d0 + l16) * 16 + quad * 8];
        f32x4 zacc = {0.f, 0.f, 0.f, 0.f};
        f32x4 ST0 = __builtin_amdgcn_mfma_f32_16x16x32_bf16(kf, qf, zacc, 0, 0, 0);
        float pf0 = fexp2(ST0[0]);
        float pf1 = fexp2(ST0[1]);
        float pf2 = fexp2(ST0[2]);
        float pf3 = fexp2(ST0[3]);
        lsum += (pf0 + pf1) + (pf2 + pf3);
        *(int2*)&plrow[quad * 4] = pack4(pf0, pf1, pf2, pf3);
        int2 z2 = {0, 0};
        *(int2*)&plrow[16 + quad * 4] = z2;
        *(int2*)&plrow[32 + quad * 4] = z2;
        *(int2*)&plrow[48 + quad * 4] = z2;
        #pragma unroll
        for (int s = 0; s < 2; ++s) {
            frag8 vf = *(const frag8*)&Vh[(size_t)l16 * HW + d0 + s * 32 + quad * 8];
            frag8 pf = *(const frag8*)&plrow[s * 32 + quad * 8];
            Oacc = __builtin_amdgcn_mfma_f32_16x16x32_bf16(vf, pf, Oacc, 0, 0, 0);
        }
    }

    lsum += __shfl_xor(lsum, 16);
    lsum += __shfl_xor(lsum, 32);

    if (dq > 0) {
        int slot = dq - 1;
        #pragma unroll
        for (int r = 0; r < 4; ++r)
            Ocomb[slot][qw][quad * 4 + r][l16] = Oacc[r];
        if (quad == 0) Lcomb[slot][qw][l16] = lsum;
    }
    __syncthreads();
    if (dq == 0) {
        #pragma unroll
        for (int s = 0; s < 3; ++s) {
            #pragma unroll
            for (int r = 0; r < 4; ++r)
                Oacc[r] += Ocomb[s][qw][quad * 4 + r][l16];
            lsum += Lcomb[s][qw][l16];
        }
        if (qtok < HW) {
            float inv = frcp(lsum);
            int2 pk = pack4(Oacc[0] * inv, Oacc[1] * inv, Oacc[2] * inv, Oacc[3] * inv);
            short* An = (short*)A + (size_t)n * HW * CH;
            *(int2*)&An[(size_t)qtok * CH + head * 16 + quad * 4] = pk;
        }
    }
}

extern "C" void kernel_launch(void* const* d_in, const int* in_sizes, int n_in,
                              void* d_out, int out_size, void* d_ws, size_t ws_size,
                              hipStream_t stream) {
    char* ws = (char*)d_ws;
    bf16*  Wst  = (bf16*)(ws + 256);          // 327680 bf16
    float* Bst  = (float*)(ws + 655616);      // 768 f32
    bf16*  XT   = (bf16*)(ws + 1048576);      // channel-last [n][1296][128]
    bf16*  Zb   = XT + TT;
    bf16*  Qb   = Zb + TT;                    // head-grouped [n][8][1296][16], LOG2E-scaled
    bf16*  Kb   = Qb + TT;                    // head-grouped
    bf16*  Vb   = Kb + TT;                    // channel-first [n][128][1296]
    bf16*  Ab   = Vb + TT;                    // ~17 MB total

    k_prep<<<1284, 256, 0, stream>>>(d_in[1], d_in[3], d_in[5], d_in[6], d_in[7],
                                     d_in[8], d_in[12], d_in[14], d_in[16],
                                     d_in[2], d_in[4], d_in[9], d_in[13], d_in[15], d_in[17],
                                     Wst, Bst);
    // n on blockIdx.x (gridDim.x == 8): per-batch XCD locality
    k_inm<<<dim3(8, 41, 4), 256, 0, stream>>>(d_in[0], d_in[1], Wst, Bst, XT);
    k_cq <<<dim3(8, 41), 512, 0, stream>>>(XT, Wst + 16384, Wst + 163840, Bst + 128,
                                           Zb, Qb, Kb, Vb);
    k_attn<<<dim3(8, 21, 8), 1024, 0, stream>>>(Qb, Kb, Vb, Ab);
    k_go <<<dim3(8, 41), 512, 0, stream>>>(Zb, Ab, Wst + 212992, Bst + 256,
                                           Wst + 311296, Bst + 640, d_out, d_in[1]);
}